// Round 4
// baseline (1730.847 us; speedup 1.0000x reference)
//
#include <hip/hip_runtime.h>
#include <cstdint>

#define B_SZ 256
#define T_SZ 256
#define I_SZ 512
#define H_SZ 512
#define HALF 256

typedef __attribute__((ext_vector_type(8))) __bf16 bf16x8;
typedef __attribute__((ext_vector_type(8))) short short8;
typedef __attribute__((ext_vector_type(4))) float f32x4;
typedef __attribute__((ext_vector_type(4))) unsigned int uint4v;

// barrier WITHOUT the vmcnt(0) drain __syncthreads would emit: LDS ordering
// only. Keeps out[]-stores / x-prefetch loads in flight across the barrier.
#define LGKM_BARRIER() __asm__ __volatile__("s_waitcnt lgkmcnt(0)\ns_barrier" ::: "memory")
#define COMPILER_FENCE() __asm__ __volatile__("" ::: "memory")

__device__ __forceinline__ unsigned short f2bf(float f) {
  unsigned int u = __float_as_uint(f);
  u = (u + 0x7FFFu + ((u >> 16) & 1u)) >> 16;   // RNE
  return (unsigned short)u;
}
__device__ __forceinline__ float sigm(float x) {
  return __builtin_amdgcn_rcpf(1.f + __expf(-x));
}
__device__ __forceinline__ float tanh_(float x) {
  float ax = fabsf(x);
  float e = __expf(-2.f * ax);
  float r = (1.f - e) * __builtin_amdgcn_rcpf(1.f + e);
  return copysignf(r, x);
}

// ---------------- prepass: fp32 -> bf16 (8 elems/thread) ----------------
__global__ void cvt_f32_bf16(const float* __restrict__ src, unsigned short* __restrict__ dst) {
  long i = ((long)blockIdx.x * 256 + threadIdx.x) * 8;
  float4 a = *(const float4*)(src + i);
  float4 b = *(const float4*)(src + i + 4);
  unsigned int w0 = (unsigned)f2bf(a.x) | ((unsigned)f2bf(a.y) << 16);
  unsigned int w1 = (unsigned)f2bf(a.z) | ((unsigned)f2bf(a.w) << 16);
  unsigned int w2 = (unsigned)f2bf(b.x) | ((unsigned)f2bf(b.y) << 16);
  unsigned int w3 = (unsigned)f2bf(b.z) | ((unsigned)f2bf(b.w) << 16);
  uint4v v = {w0, w1, w2, w3};
  *(uint4v*)(dst + i) = v;
}

// ---------------- prepass: h0 -> tagged u64 words (tag = 0) ----------------
__global__ void cvt_h0_tag(const float* __restrict__ h0, unsigned long long* __restrict__ dst) {
  int i = blockIdx.x * 256 + threadIdx.x;          // 0..65535 words
  unsigned int pw = (unsigned)f2bf(h0[2 * i]) | ((unsigned)f2bf(h0[2 * i + 1]) << 16);
  dst[i] = (unsigned long long)pw;                 // high 32 = tag 0
}

// ---------------- prepass: pack W_ih / W_hh into per-lane MFMA-B fragment order ----
__global__ void pack_w(const float* __restrict__ Wih, const float* __restrict__ Whh,
                       unsigned short* __restrict__ wp, unsigned short* __restrict__ hp) {
  int id = blockIdx.x * 256 + threadIdx.x;        // 0 .. 262143
  int cid = id & 131071;
  const float* W = (id < 131072) ? Wih : Whh;
  unsigned short* D = (id < 131072) ? wp : hp;
  int l  = cid & 63;
  int ks = (cid >> 6) & 15;
  int nt = (cid >> 10) & 1;
  int w  = (cid >> 11) & 3;
  int hg = (cid >> 13) & 15;
  int row = w * 512 + hg * 32 + nt * 16 + (l & 15);
  int k0  = ks * 32 + (l >> 4) * 8;
  const float* src = W + (long)row * 512 + k0;
  unsigned int wd[4];
#pragma unroll
  for (int j = 0; j < 4; ++j) {
    unsigned int lo = f2bf(src[2 * j]);
    unsigned int hi = f2bf(src[2 * j + 1]);
    wd[j] = lo | (hi << 16);
  }
  uint4v v = {wd[0], wd[1], wd[2], wd[3]};
  *(uint4v*)(D + (long)cid * 8) = v;
}

template <int SCOPE>
__device__ __forceinline__ unsigned long long ld64(const unsigned long long* p) {
  return __hip_atomic_load(p, __ATOMIC_RELAXED, SCOPE);
}
template <int SCOPE>
__device__ __forceinline__ void st64v(unsigned long long* p, unsigned long long v) {
  __hip_atomic_store(p, v, __ATOMIC_RELAXED, SCOPE);
}

// ---------------- the whole recurrence, templated on memory scope ----------------
// Sync protocol per step t:
//   producer wave (block hg, wave w): after ITS bulk-consume of parity (t+1)&1,
//   stores its tagged data words ((t+1)<<32 | bf16x2) to parity t&1, then
//   (program order) one sentinel word sent[bg*64+hg*4+w] = t+1.
//   consumer: (a) cheap gate: lane l polls sent[bg*64+l] >= t  (512 B/iter/block
//   instead of round-3's 32 KB/iter -> no L2 saturation); (b) bulk tagged load
//   with verify-redo (tag == t) -- this full verify is ALSO the correctness
//   guarantee (producer can only clobber parity p after every peer WAVE's data
//   tags of the previous generation were published, which happens after each
//   wave's own consume). Deadlock-free by induction as in round 3.
template <int SCOPE>
__device__ __forceinline__ void lstm_body(
    const unsigned short* __restrict__ xb, const float* __restrict__ c0,
    const float* __restrict__ b_ih, const float* __restrict__ b_hh,
    const unsigned short* __restrict__ wihp, const unsigned short* __restrict__ whhp,
    unsigned long long* __restrict__ hw64, unsigned long long* __restrict__ sent,
    float* __restrict__ out, float* glds, unsigned int* hpad, int bg, int hg)
{
  const int tid  = threadIdx.x;
  const int lane = tid & 63;
  const int w    = tid >> 6;
  const int s0   = hg * 32;
  const int q    = lane >> 4;
  const int c16  = lane & 15;

  // resident weight fragments (256 VGPRs)
  bf16x8 wih[2][16], whh[2][16];
#pragma unroll
  for (int nt = 0; nt < 2; ++nt) {
#pragma unroll
    for (int ks = 0; ks < 16; ++ks) {
      int idc = ((hg * 4 + w) * 2 + nt) * 16 + ks;
      long off = ((long)(idc * 64 + lane)) * 8;
      wih[nt][ks] = __builtin_bit_cast(bf16x8, *(const short8*)(wihp + off));
      whh[nt][ks] = __builtin_bit_cast(bf16x8, *(const short8*)(whhp + off));
    }
  }

  const int jj  = tid & 31;
  const int bl0 = tid >> 5;            // 0..7
  const int bglob0 = bg * 16 + bl0;
  const int bglob1 = bglob0 + 8;
  float bias_v[4];
#pragma unroll
  for (int g = 0; g < 4; ++g)
    bias_v[g] = b_ih[g * 512 + s0 + jj] + b_hh[g * 512 + s0 + jj];
  float cst0 = c0[(long)bglob0 * H_SZ + s0 + jj];
  float cst1 = c0[(long)bglob1 * H_SZ + s0 + jj];
  float m0 = -INFINITY, m1 = -INFINITY;
  float h0p = 0.f, h1p = 0.f;          // h of previous step (for delayed out stores)

  const unsigned short* xbase = xb + (long)(bg * 16 + c16) * T_SZ * I_SZ + q * 8;
  unsigned long long* gsent = sent + bg * 64;

  // preload x fragments for t = 0 (single register buffer, reloaded mid-step)
  bf16x8 xreg[16];
#pragma unroll
  for (int ks = 0; ks < 16; ++ks)
    xreg[ks] = __builtin_bit_cast(bf16x8, *(const short8*)(xbase + ks * 32));

#pragma unroll 1
  for (int t = 0; t < T_SZ; ++t) {
    f32x4 a0a = {0,0,0,0}, a0b = {0,0,0,0}, a1a = {0,0,0,0}, a1b = {0,0,0,0};

    // phase A: x projection from registers (4 independent 8-deep chains)
#pragma unroll
    for (int ks = 0; ks < 8; ++ks) {
      a0a = __builtin_amdgcn_mfma_f32_16x16x32_bf16(xreg[ks],   wih[0][ks],   a0a, 0, 0, 0);
      a1a = __builtin_amdgcn_mfma_f32_16x16x32_bf16(xreg[ks],   wih[1][ks],   a1a, 0, 0, 0);
      a0b = __builtin_amdgcn_mfma_f32_16x16x32_bf16(xreg[ks+8], wih[0][ks+8], a0b, 0, 0, 0);
      a1b = __builtin_amdgcn_mfma_f32_16x16x32_bf16(xreg[ks+8], wih[1][ks+8], a1b, 0, 0, 0);
    }

    // phase B1: sentinel gate — 1 load per lane per iteration
    {
      const unsigned long long* sp = gsent + lane;
      unsigned long long sv = ld64<SCOPE>(sp);
      while (sv < (unsigned long long)t) sv = ld64<SCOPE>(sp);
    }
    COMPILER_FENCE();

    // phase B2: bulk tagged fetch + verify-redo (correctness anchor)
    {
      const unsigned long long* src = hw64 + ((t + 1) & 1) * 65536 + bg * 4096;
      unsigned long long v[16];
#pragma unroll
      for (int i = 0; i < 16; ++i)
        v[i] = ld64<SCOPE>(src + i * 256 + tid);
      bool redo = true;
      while (redo) {
        redo = false;
#pragma unroll
        for (int i = 0; i < 16; ++i) {
          if ((unsigned)(v[i] >> 32) != (unsigned)t) {
            v[i] = ld64<SCOPE>(src + i * 256 + tid);
            redo = true;
          }
        }
      }
#pragma unroll
      for (int i = 0; i < 16; ++i)
        hpad[i * 260 + tid] = (unsigned int)v[i];
    }

    // issue x reload for t+1 now: latency hides under phases C/D/E,
    // and is fully drained before the next step's sentinel poll.
    {
      const unsigned short* xn = xbase + (long)((t < T_SZ - 1) ? t + 1 : t) * I_SZ;
#pragma unroll
      for (int ks = 0; ks < 16; ++ks)
        xreg[ks] = __builtin_bit_cast(bf16x8, *(const short8*)(xn + ks * 32));
    }

    // delayed out[] stores for step t-1 (HBM latency off the critical path)
    if (t > 0) {
#pragma unroll
      for (int it = 0; it < 2; ++it) {
        int bgl = bg * 16 + bl0 + it * 8;
        if (hg < 8) {
          float mm = it ? m1 : m0;
          out[(long)bgl * (T_SZ * HALF) + (t - 1) * HALF + s0 + jj] = mm;
        } else {
          float hp = it ? h1p : h0p;
          out[(long)(256 + bgl) * (T_SZ * HALF) + (t - 1) * HALF + (s0 - 256) + jj] = hp;
        }
      }
    }

    LGKM_BARRIER();   // hpad visible to all waves; no vmcnt drain

    // phase C: recurrent projection from LDS
    const unsigned int* hrow = hpad + c16 * 260;
#pragma unroll
    for (int ks = 0; ks < 8; ++ks) {
      bf16x8 ha = __builtin_bit_cast(bf16x8, *(const uint4v*)(hrow + ks * 16 + q * 4));
      bf16x8 hb = __builtin_bit_cast(bf16x8, *(const uint4v*)(hrow + (ks + 8) * 16 + q * 4));
      a0a = __builtin_amdgcn_mfma_f32_16x16x32_bf16(ha, whh[0][ks],   a0a, 0, 0, 0);
      a1a = __builtin_amdgcn_mfma_f32_16x16x32_bf16(ha, whh[1][ks],   a1a, 0, 0, 0);
      a0b = __builtin_amdgcn_mfma_f32_16x16x32_bf16(hb, whh[0][ks+8], a0b, 0, 0, 0);
      a1b = __builtin_amdgcn_mfma_f32_16x16x32_bf16(hb, whh[1][ks+8], a1b, 0, 0, 0);
    }

    // phase D: combine halves, gates -> LDS
#pragma unroll
    for (int r = 0; r < 4; ++r) {
      glds[w * 528 + (q * 4 + r) * 33 + c16]      = a0a[r] + a0b[r];
      glds[w * 528 + (q * 4 + r) * 33 + 16 + c16] = a1a[r] + a1b[r];
    }
    LGKM_BARRIER();

    // phase E: cell math, publish h words + per-wave sentinel
    float hv0, hv1;
#pragma unroll
    for (int it = 0; it < 2; ++it) {
      int b = bl0 + it * 8;
      float gi = glds[0 * 528 + b * 33 + jj] + bias_v[0];
      float gf = glds[1 * 528 + b * 33 + jj] + bias_v[1];
      float gg = glds[2 * 528 + b * 33 + jj] + bias_v[2];
      float go = glds[3 * 528 + b * 33 + jj] + bias_v[3];
      float& cs = it ? cst1 : cst0;
      cs = sigm(gf) * cs + sigm(gi) * tanh_(gg);
      float h = sigm(go) * tanh_(cs);
      if (it) hv1 = h; else hv0 = h;
    }
    {
      float po0 = __shfl_xor(hv0, 1);
      float po1 = __shfl_xor(hv1, 1);
      if (!(jj & 1)) {
        unsigned long long tagw = (unsigned long long)(t + 1) << 32;
        unsigned long long w0 = tagw | ((unsigned)f2bf(hv0) | ((unsigned)f2bf(po0) << 16));
        unsigned long long w1 = tagw | ((unsigned)f2bf(hv1) | ((unsigned)f2bf(po1) << 16));
        unsigned long long* d0 = hw64 + (t & 1) * 65536 + bg * 4096
                               + bl0 * 256 + hg * 16 + (jj >> 1);
        st64v<SCOPE>(d0, w0);
        st64v<SCOPE>(d0 + 8 * 256, w1);
      }
      COMPILER_FENCE();              // keep sentinel issue after data stores
      if (lane == 0)
        st64v<SCOPE>(gsent + hg * 4 + w, (unsigned long long)(t + 1));
    }
    // update running max AFTER the publish is in flight; save h for delayed store
    m0 = fmaxf(m0, hv0);
    m1 = fmaxf(m1, hv1);
    h0p = hv0; h1p = hv1;
  }

  // tail: out for t = 255 + final h/c
#pragma unroll
  for (int it = 0; it < 2; ++it) {
    int bgl = bg * 16 + bl0 + it * 8;
    float h = it ? h1p : h0p;
    float cs = it ? cst1 : cst0;
    if (hg < 8) {
      float mm = it ? m1 : m0;
      out[(long)bgl * (T_SZ * HALF) + 255 * HALF + s0 + jj] = mm;
    } else {
      out[(long)(256 + bgl) * (T_SZ * HALF) + 255 * HALF + (s0 - 256) + jj] = h;
    }
    out[33554432L + (long)bgl * H_SZ + s0 + jj] = h;
    out[33554432L + 131072L + (long)bgl * H_SZ + s0 + jj] = cs;
  }
}

__global__ __launch_bounds__(256, 1) void lstm_main(
    const unsigned short* __restrict__ xb, const float* __restrict__ c0,
    const float* __restrict__ b_ih, const float* __restrict__ b_hh,
    const unsigned short* __restrict__ wihp, const unsigned short* __restrict__ whhp,
    unsigned long long* __restrict__ hw64, unsigned long long* __restrict__ sent,
    unsigned long long* __restrict__ cnt64, float* __restrict__ out)
{
  const int tid = threadIdx.x;
  const int bg  = blockIdx.x & 15;
  const int hg  = blockIdx.x >> 4;

  __shared__ float glds[4 * 528];
  __shared__ unsigned int hpad[16 * 260];
  __shared__ int s_path;

  // one-time scope handshake: all 16 blocks of this group on one XCD?
  int xcd;
  asm volatile("s_getreg_b32 %0, hwreg(20, 0, 32)" : "=s"(xcd));
  xcd &= 15;
  if (tid == 0) {
    unsigned long long inc = 1ull << (8 * xcd);
    __hip_atomic_fetch_add(&cnt64[bg * 8], inc, __ATOMIC_RELAXED, __HIP_MEMORY_SCOPE_SYSTEM);
    unsigned long long m;
    do {
      __builtin_amdgcn_s_sleep(2);
      m = __hip_atomic_load(&cnt64[bg * 8], __ATOMIC_RELAXED, __HIP_MEMORY_SCOPE_SYSTEM);
    } while ((unsigned)((m * 0x0101010101010101ull) >> 56) < 16);
    s_path = (m == (16ull << (8 * xcd))) ? 1 : 0;
  }
  __syncthreads();

  if (s_path)
    lstm_body<__HIP_MEMORY_SCOPE_AGENT>(xb, c0, b_ih, b_hh, wihp, whhp,
                                        hw64, sent, out, glds, hpad, bg, hg);
  else
    lstm_body<__HIP_MEMORY_SCOPE_SYSTEM>(xb, c0, b_ih, b_hh, wihp, whhp,
                                         hw64, sent, out, glds, hpad, bg, hg);
}

extern "C" void kernel_launch(void* const* d_in, const int* in_sizes, int n_in,
                              void* d_out, int out_size, void* d_ws, size_t ws_size,
                              hipStream_t stream) {
  const float* x   = (const float*)d_in[0];
  const float* h0  = (const float*)d_in[1];
  const float* c0  = (const float*)d_in[2];
  const float* Wih = (const float*)d_in[3];
  const float* Whh = (const float*)d_in[4];
  const float* bih = (const float*)d_in[5];
  const float* bhh = (const float*)d_in[6];
  float* out = (float*)d_out;

  char* ws = (char*)d_ws;
  unsigned short* xb       = (unsigned short*)(ws);                // 67,108,864 B
  unsigned short* wihp     = (unsigned short*)(ws + 67108864);     //  2,097,152 B
  unsigned short* whhp     = (unsigned short*)(ws + 69206016);     //  2,097,152 B
  unsigned long long* hw   = (unsigned long long*)(ws + 71303168); //  1,048,576 B
  unsigned long long* sent = (unsigned long long*)(ws + 72351744); //      8,192 B
  unsigned long long* cn   = (unsigned long long*)(ws + 72359936); //      1,024 B

  hipMemsetAsync(sent, 0, 9216, stream);                       // sent + cnt
  cvt_f32_bf16<<<16384, 256, 0, stream>>>(x, xb);              // x -> bf16
  cvt_h0_tag<<<256, 256, 0, stream>>>(h0, hw + 65536);         // h0 -> buf 1, tag 0
  pack_w<<<1024, 256, 0, stream>>>(Wih, Whh, wihp, whhp);
  lstm_main<<<256, 256, 0, stream>>>(xb, c0, bih, bhh, wihp, whhp, hw, sent, cn, out);
}